// Round 7
// baseline (205.531 us; speedup 1.0000x reference)
//
#include <hip/hip_runtime.h>
#include <math.h>

// ---------------------------------------------------------------------------
// GMM log-likelihood, N=2M x D=16, K=32, out = mean_n logsumexp_k loglik[n,k]
//
// loglik[n,k] = sum_{ij} (-0.5 P_ij) x_i x_j + (P mu)_i x_i + c_k  (log2 dom.)
// LINEAR in phi(x) = [ x_i*x_j (256), x_i (16), 1 ] -> 18 K16-chunks of one
// chained mfma_f32_32x32x16_f16 (M=32 = all comps; c_k folded in as chunk 17).
// C layout (HW-verified): col=lane&31 (point), row=(reg&3)+8*(reg>>2)+4*(lane>>5).
// W resident in registers (72 VGPRs, gfx950 unified file, (256,2) -> 256 regs).
//
// R7: R3-R6 all had each lane loading its own point's 64 B -> lanes stride
// 64 B within each dwordx4 -> 32-64 cache lines per instruction at 16 B each
// -> ~256-512 VMEM transactions per pair-iter (~26 us/CU of TA serialization,
// the invariant ~60 us main). Fix: SPLIT each point across the lane pair:
// lo lane loads floats 0-7, hi lane floats 8-15; halves exchanged with
// v_permlane32_swap (VALU-only). 2 lanes per 64-B line, 4 instr/iter ->
// ~4x fewer transactions. Own half == this lane's B-frag second factor
// (xs sel eliminated). Prefetch depth 2 (two staging slots).
// ---------------------------------------------------------------------------

#define LOG_2PI 1.8378770664093453f
#define INV_LN2 1.4426950408889634f
#define LN2_D   0.6931471805599453

typedef float    float4v __attribute__((ext_vector_type(4)));
typedef float    f32x16  __attribute__((ext_vector_type(16)));
typedef _Float16 f16x8   __attribute__((ext_vector_type(8)));
typedef _Float16 f16x2   __attribute__((ext_vector_type(2)));

union H8 { f16x8 h8; f16x2 h2[4]; };

#if __has_builtin(__builtin_amdgcn_exp2f)
#define EXP2F(x) __builtin_amdgcn_exp2f(x)
#else
#define EXP2F(x) exp2f(x)
#endif
#if __has_builtin(__builtin_amdgcn_logf)
#define LOG2F(x) __builtin_amdgcn_logf(x)
#else
#define LOG2F(x) log2f(x)
#endif

static __device__ __forceinline__ f16x2 pk2(float a, float b) {
#if __has_builtin(__builtin_amdgcn_cvt_pkrtz)
  return __builtin_bit_cast(f16x2, __builtin_amdgcn_cvt_pkrtz(a, b));
#else
  f16x2 r; r[0] = (_Float16)a; r[1] = (_Float16)b; return r;
#endif
}

// partner-lane (lane^32) value of a 32-bit payload, VALU-only on gfx950
static __device__ __forceinline__ unsigned swapd(unsigned u, bool lo) {
#if __has_builtin(__builtin_amdgcn_permlane32_swap)
  typedef unsigned u32x2 __attribute__((ext_vector_type(2)));
  u32x2 r = __builtin_amdgcn_permlane32_swap(u, u, false, false);
  return lo ? r[1] : r[0];
#else
  return (unsigned)__shfl_xor((int)u, 32, 64);
#endif
}
static __device__ __forceinline__ float partner32(float x, bool lo) {
  return __builtin_bit_cast(float, swapd(__builtin_bit_cast(unsigned, x), lo));
}
static __device__ __forceinline__ f16x2 swap2(f16x2 v, bool lo) {
  return __builtin_bit_cast(f16x2, swapd(__builtin_bit_cast(unsigned, v), lo));
}
static __device__ __forceinline__ f16x2 sel2(bool c, f16x2 a, f16x2 b) {
  unsigned ua = __builtin_bit_cast(unsigned, a);
  unsigned ub = __builtin_bit_cast(unsigned, b);
  return __builtin_bit_cast(f16x2, c ? ua : ub);
}

// ---------------------------------------------------------------------------
// Setup: per component k: cov = A A^T, Cholesky L, Linv, P = Linv^T Linv.
// W in 32x32x16 A-frag order: lane l holds A[m=l&31][k16 = 8*(l>>5)+v],
// chunk c covers feature k = 16c + 8h + v.
// chunks 0..15: (i,j)=(c, 8h+v) -> -0.5/ln2 * P[i][j]
// chunk 16: linear, feature i=8h+v -> (P mu)_i / ln2
// chunk 17: constant, slot (h=0,v=0) -> c2[m]; all other slots 0
// ---------------------------------------------------------------------------
__global__ void setup_kernel(const float* __restrict__ means,
                             const float* __restrict__ cov_parts,
                             const float* __restrict__ log_weights,
                             _Float16* __restrict__ W)
{
  const int k = blockIdx.x;
  const int i = threadIdx.x;

  __shared__ float sA[16][17];
  __shared__ float sC[16][17];
  __shared__ float sMu[16];
  __shared__ float sR[16];

  if (i < 16) {
    #pragma unroll
    for (int j = 0; j < 16; ++j) sA[i][j] = cov_parts[(k*16 + i)*16 + j];
    sMu[i] = means[k*16 + i];
  }
  __syncthreads();

  if (i < 16) {
    #pragma unroll
    for (int j = 0; j < 16; ++j) {
      float acc = 0.f;
      #pragma unroll
      for (int l = 0; l < 16; ++l) acc += sA[i][l] * sA[j][l];
      sC[i][j] = acc;
    }
  }
  __syncthreads();

  for (int j = 0; j < 16; ++j) {
    if (i == j) {
      float d = sC[j][j];
      for (int l = 0; l < j; ++l) d -= sC[j][l]*sC[j][l];
      sC[j][j] = sqrtf(d);
    }
    __syncthreads();
    if (i < 16 && i > j) {
      float a = sC[i][j];
      for (int l = 0; l < j; ++l) a -= sC[i][l]*sC[j][l];
      sC[i][j] = a / sC[j][j];
    }
    __syncthreads();
  }

  if (i < 16) {
    float y[16];
    #pragma unroll
    for (int r = 0; r < 16; ++r) {
      float a = (r == i) ? 1.f : 0.f;
      #pragma unroll
      for (int l = 0; l < r; ++l) a -= sC[r][l] * y[l];
      y[r] = a / sC[r][r];
    }
    #pragma unroll
    for (int r = 0; r < 16; ++r) sA[r][i] = y[r];
  }
  __syncthreads();

  if (i < 16) {
    float p[16];
    #pragma unroll
    for (int j = 0; j < 16; ++j) {
      float acc = 0.f;
      #pragma unroll
      for (int l = 0; l < 16; ++l) acc += sA[l][i] * sA[l][j];
      p[j] = acc;
    }
    float ri = 0.f;
    #pragma unroll
    for (int j = 0; j < 16; ++j) ri += p[j] * sMu[j];
    sR[i] = ri;

    #pragma unroll
    for (int j = 0; j < 16; ++j) {
      W[(size_t)(i*64 + (k + 32*(j >> 3)))*8 + (j & 7)] =
          (_Float16)(-0.5f * INV_LN2 * p[j]);
    }
    W[(size_t)(16*64 + (k + 32*(i >> 3)))*8 + (i & 7)] =
        (_Float16)(INV_LN2 * ri);
  }
  __syncthreads();

  if (i == 0) {
    float logdet = 0.f;
    #pragma unroll
    for (int j = 0; j < 16; ++j) logdet += __logf(sC[j][j]);
    float mupmu = 0.f;
    #pragma unroll
    for (int j = 0; j < 16; ++j) mupmu += sMu[j] * sR[j];
    float lw = log_weights[k];
    float c2v = INV_LN2 * (-0.5f*(mupmu + 16.f*LOG_2PI) - logdet + lw*lw);
    #pragma unroll
    for (int v = 0; v < 8; ++v) {
      W[(size_t)(17*64 + k)*8 + v]      = (v == 0) ? (_Float16)c2v : (_Float16)0.f;
      W[(size_t)(17*64 + k + 32)*8 + v] = (_Float16)0.f;
    }
  }
}

// ---------------------------------------------------------------------------
__global__ __launch_bounds__(256, 2) void main_kernel(
    const float* __restrict__ data,
    const _Float16* __restrict__ W,
    float* __restrict__ partials,
    int npairs)
{
  const int lane = threadIdx.x & 63;
  const int n32  = lane & 31;
  const bool lo  = lane < 32;
  const int gwave  = (int)((blockIdx.x * blockDim.x + threadIdx.x) >> 6);
  const int nwaves = (int)((gridDim.x * blockDim.x) >> 6);

  // W fragments resident in registers (72 regs)
  f16x8 Wf[18];
  #pragma unroll
  for (int c = 0; c < 18; ++c)
    Wf[c] = *(const f16x8*)(W + (size_t)(c*64 + lane)*8);

  // constant B fragment for the c2 chunk: slot (h=0,v=0) = 1
  H8 bC;
  #pragma unroll
  for (int j = 0; j < 4; ++j) bC.h2[j] = pk2(0.f, 0.f);
  if (lo) bC.h2[0] = pk2(1.f, 0.f);

  float accsum = 0.f;

  // pair p covers points [p*64, p*64+64): tile A point = p*64+n32 (own half
  // at +h*32), tile B point = p*64+32+n32 (at +2048).
  const char* base = (const char*)data + ((size_t)n32*64 + (lo ? 0 : 32));
  auto paddr = [&](int p) { return base + (size_t)p*4096; };

  float4v sa0[2], sa1[2], sb0[2], sb1[2];   // two staging slots, 32 B/lane each

  {
    const char* q0 = (gwave           < npairs) ? paddr(gwave)          : base;
    const char* q1 = (gwave + nwaves  < npairs) ? paddr(gwave + nwaves) : base;
    sa0[0] = *(const float4v*)(q0);        sa1[0] = *(const float4v*)(q0 + 16);
    sb0[0] = *(const float4v*)(q0 + 2048); sb1[0] = *(const float4v*)(q0 + 2064);
    sa0[1] = *(const float4v*)(q1);        sa1[1] = *(const float4v*)(q1 + 16);
    sb0[1] = *(const float4v*)(q1 + 2048); sb1[1] = *(const float4v*)(q1 + 2064);
  }

  int p = gwave;
  while (p < npairs) {
    #pragma unroll
    for (int slot = 0; slot < 2; ++slot) {
      if (p >= npairs) break;

      // own-half f16 conversion (4 regs/tile) — these ARE the B second factors
      f16x2 ownA[4], ownB[4];
      ownA[0] = pk2(sa0[slot][0], sa0[slot][1]);
      ownA[1] = pk2(sa0[slot][2], sa0[slot][3]);
      ownA[2] = pk2(sa1[slot][0], sa1[slot][1]);
      ownA[3] = pk2(sa1[slot][2], sa1[slot][3]);
      ownB[0] = pk2(sb0[slot][0], sb0[slot][1]);
      ownB[1] = pk2(sb0[slot][2], sb0[slot][3]);
      ownB[2] = pk2(sb1[slot][0], sb1[slot][1]);
      ownB[3] = pk2(sb1[slot][2], sb1[slot][3]);

      // reload this slot for pair p + 2*nwaves (wave-uniform guard)
      {
        int np_ = p + 2*nwaves;
        const char* q = (np_ < npairs) ? paddr(np_) : base;
        sa0[slot] = *(const float4v*)(q);        sa1[slot] = *(const float4v*)(q + 16);
        sb0[slot] = *(const float4v*)(q + 2048); sb1[slot] = *(const float4v*)(q + 2064);
      }

      // other-half via permlane32_swap; xh = full point in f16 pairs
      f16x2 xhA[8], xhB[8];
      #pragma unroll
      for (int j = 0; j < 4; ++j) {
        f16x2 oA = swap2(ownA[j], lo);
        f16x2 oB = swap2(ownB[j], lo);
        xhA[j]   = sel2(lo, ownA[j], oA);
        xhA[4+j] = sel2(lo, oA, ownA[j]);
        xhB[j]   = sel2(lo, ownB[j], oB);
        xhB[4+j] = sel2(lo, oB, ownB[j]);
      }

      f32x16 accA, accB;
      #pragma unroll
      for (int r = 0; r < 16; ++r) { accA[r] = 0.f; accB[r] = 0.f; }

      #pragma unroll
      for (int c = 0; c < 16; ++c) {
        _Float16 xiA = xhA[c >> 1][c & 1];
        H8 bA;
        #pragma unroll
        for (int j = 0; j < 4; ++j) bA.h2[j] = ownA[j] * xiA;   // v_pk_mul_f16
        accA = __builtin_amdgcn_mfma_f32_32x32x16_f16(Wf[c], bA.h8, accA, 0, 0, 0);
        _Float16 xiB = xhB[c >> 1][c & 1];
        H8 bB;
        #pragma unroll
        for (int j = 0; j < 4; ++j) bB.h2[j] = ownB[j] * xiB;
        accB = __builtin_amdgcn_mfma_f32_32x32x16_f16(Wf[c], bB.h8, accB, 0, 0, 0);
      }
      {   // linear chunk: features = own half
        H8 bA, bB;
        #pragma unroll
        for (int j = 0; j < 4; ++j) { bA.h2[j] = ownA[j]; bB.h2[j] = ownB[j]; }
        accA = __builtin_amdgcn_mfma_f32_32x32x16_f16(Wf[16], bA.h8, accA, 0, 0, 0);
        accB = __builtin_amdgcn_mfma_f32_32x32x16_f16(Wf[16], bB.h8, accB, 0, 0, 0);
      }
      {   // c2 chunk
        accA = __builtin_amdgcn_mfma_f32_32x32x16_f16(Wf[17], bC.h8, accA, 0, 0, 0);
        accB = __builtin_amdgcn_mfma_f32_32x32x16_f16(Wf[17], bC.h8, accB, 0, 0, 0);
      }

      // epilogue: logsumexp (log2 domain), acc already includes c2
      {
        float m = accA[0];
        #pragma unroll
        for (int r = 1; r < 16; ++r) m = fmaxf(m, accA[r]);
        m = fmaxf(m, partner32(m, lo));
        float s = 0.f;
        #pragma unroll
        for (int r = 0; r < 16; ++r) s += EXP2F(accA[r] - m);
        s += partner32(s, lo);
        accsum += m + LOG2F(s);
      }
      {
        float m = accB[0];
        #pragma unroll
        for (int r = 1; r < 16; ++r) m = fmaxf(m, accB[r]);
        m = fmaxf(m, partner32(m, lo));
        float s = 0.f;
        #pragma unroll
        for (int r = 0; r < 16; ++r) s += EXP2F(accB[r] - m);
        s += partner32(s, lo);
        accsum += m + LOG2F(s);
      }

      p += nwaves;
    }
  }

  #pragma unroll
  for (int off = 1; off <= 32; off <<= 1)
    accsum += __shfl_xor(accsum, off, 64);

  __shared__ float wsum[4];
  const int wid = (int)(threadIdx.x >> 6);
  if ((threadIdx.x & 63) == 0) wsum[wid] = accsum;
  __syncthreads();
  if (threadIdx.x == 0)
    partials[blockIdx.x] = wsum[0] + wsum[1] + wsum[2] + wsum[3];
}

// ---------------------------------------------------------------------------
__global__ void reduce_kernel(const float* __restrict__ partials, int n,
                              float* __restrict__ out, double scale)
{
  __shared__ double sd[256];
  double a = 0.0;
  for (int idx = threadIdx.x; idx < n; idx += 256) a += (double)partials[idx];
  sd[threadIdx.x] = a;
  __syncthreads();
  for (int s = 128; s > 0; s >>= 1) {
    if ((int)threadIdx.x < s) sd[threadIdx.x] += sd[threadIdx.x + s];
    __syncthreads();
  }
  if (threadIdx.x == 0) out[0] = (float)(sd[0] * scale);
}

extern "C" void kernel_launch(void* const* d_in, const int* in_sizes, int n_in,
                              void* d_out, int out_size, void* d_ws, size_t ws_size,
                              hipStream_t stream)
{
  const float* data        = (const float*)d_in[0];
  const float* means       = (const float*)d_in[1];
  const float* cov_parts   = (const float*)d_in[2];
  const float* log_weights = (const float*)d_in[3];

  const int npts   = in_sizes[0] / 16;
  const int npairs = npts / 64;        // N = 2,000,000 divisible by 64

  _Float16* W      = (_Float16*)d_ws;                          // 18*64*8 halfs
  float*    partials = (float*)((char*)d_ws + (size_t)18*64*8*sizeof(_Float16));

  const int GRID = 512, BLOCK = 256;   // 2 blocks/CU, one resident round
  setup_kernel<<<32, 64, 0, stream>>>(means, cov_parts, log_weights, W);
  main_kernel<<<GRID, BLOCK, 0, stream>>>(data, W, partials, npairs);
  reduce_kernel<<<1, 256, 0, stream>>>(partials, GRID, (float*)d_out,
                                       LN2_D / (2.0 * (double)npts));
}